// Round 9
// baseline (337.342 us; speedup 1.0000x reference)
//
#include <hip/hip_runtime.h>
#include <hip/hip_bf16.h>

#define BB 4
#define NN 32
#define MM 64
#define KK 16
#define KK1 17
#define PP 128
#define CC 2

typedef unsigned short ushort_t;
typedef unsigned int uint32;
typedef __attribute__((ext_vector_type(8))) short bhalf8;
typedef __attribute__((ext_vector_type(4))) float floatx4;

__device__ __forceinline__ float fast_tanh(float x) {
    float e = __expf(2.0f * x);
    return 1.0f - 2.0f / (e + 1.0f);
}
__device__ __forceinline__ ushort_t f2b(float f) {
    uint32 u = __float_as_uint(f);
    return (ushort_t)((u + 0x8000u) >> 16);
}
__device__ __forceinline__ float b2f(ushort_t h) {
    return __uint_as_float(((uint32)h) << 16);
}

// ---------------------------------------------------------------------------
// Prep: weights -> bf16 B-operand layouts + w_ws[b*64+m][256] (xp,vp + tb0)
// ---------------------------------------------------------------------------
__global__ void prep_kernel(const float* __restrict__ tw0, const float* __restrict__ tw1,
                            const float* __restrict__ tw2, const float* __restrict__ sw0,
                            const float* __restrict__ sw1, const float* __restrict__ aw0,
                            const float* __restrict__ aw1, const float* __restrict__ tb0,
                            const float* __restrict__ bcoord,
                            ushort_t* __restrict__ W1t, ushort_t* __restrict__ W2t,
                            ushort_t* __restrict__ S0t, ushort_t* __restrict__ S1t,
                            ushort_t* __restrict__ W0a, ushort_t* __restrict__ W1a,
                            ushort_t* __restrict__ w_ws) {
    int i = blockIdx.x * 256 + threadIdx.x;
    if (i < 65536) {
        int nn = i >> 8, k = i & 255;
        W1t[i] = f2b(tw1[k * 256 + nn]);
    } else if (i < 98304) {
        int j = i - 65536; int nn = j >> 8, k = j & 255;
        W2t[j] = f2b(tw2[k * 128 + nn]);
    } else if (i < 114688) {
        S0t[i - 98304] = f2b(sw0[i - 98304]);
    } else if (i < 131072) {
        S1t[i - 114688] = f2b(sw1[i - 114688]);
    } else if (i < 133120) {
        int j = i - 131072; int nn = j >> 5, k = j & 31;
        W0a[j] = (k < 6) ? f2b(aw0[k * 64 + nn]) : (ushort_t)0;
    } else if (i < 137216) {
        int j = i - 133120; int nn = j >> 6, k = j & 63;
        W1a[j] = f2b(aw1[k * 64 + nn]);
    } else if (i < 202752) {
        int j = i - 137216;
        int m = j >> 8, c = j & 255;
        float v = bcoord[m * 4 + 0] * tw0[4 * 256 + c]
                + bcoord[m * 4 + 1] * tw0[5 * 256 + c]
                + bcoord[m * 4 + 2] * tw0[6 * 256 + c]
                + bcoord[m * 4 + 3] * tw0[7 * 256 + c]
                + tb0[c];
        w_ws[j] = f2b(v);
    }
}

// ---------------------------------------------------------------------------
// Kernel A (MFMA attn): block per (b,n,k); also emits u_ws[bn*17+k][256].
// ---------------------------------------------------------------------------
#define AH0S 72

__global__ __launch_bounds__(128) void attn_kernel(
    const float* __restrict__ phase, const float* __restrict__ posc,
    const float* __restrict__ sigma, const float* __restrict__ velc,
    const ushort_t* __restrict__ W0a, const ushort_t* __restrict__ W1a,
    const float* __restrict__ ab0, const float* __restrict__ ab1,
    const float* __restrict__ aw2, const float* __restrict__ ab2,
    const float* __restrict__ tw0, ushort_t* __restrict__ u_ws)
{
    __shared__ __align__(16) ushort_t sA0[128 * 32];
    __shared__ __align__(16) ushort_t sH0[128 * AH0S];
    __shared__ float sPL[128];
    __shared__ float sLG[128];
    __shared__ float s_red[8];

    const int tid = threadIdx.x;
    const int wave = tid >> 6;
    const int lane = tid & 63;
    const int lrow = lane & 15;
    const int lkg  = lane >> 4;

    const int blk = blockIdx.x;
    const int b = blk / (NN * KK1);
    const int rem = blk % (NN * KK1);
    const int n = rem / KK1;
    const int k = rem % KK1;

    float x0, x1, va0, va1;
    {
        const int p = tid;
        x0 = phase[(b * NN + n) * 4 + 0];
        x1 = phase[(b * NN + n) * 4 + 1];
        if (k == 0) { va0 = phase[(b * NN + n) * 4 + 2]; va1 = phase[(b * NN + n) * 4 + 3]; }
        else { va0 = velc[(b * KK + (k - 1)) * 2 + 0]; va1 = velc[(b * KK + (k - 1)) * 2 + 1]; }
        const float inv = rsqrtf(va0 * va0 + va1 * va1 + 1e-16f);
        const float ag0 = va0 * inv, ag1 = va1 * inv;
        const float px = posc[(b * PP + p) * 2 + 0];
        const float py = posc[(b * PP + p) * 2 + 1];
        const float r0 = x0 - px, r1 = x1 - py;
        const float rd = sqrtf(r0 * r0 + r1 * r1 + 1e-16f);
        const float pl = r0 * ag0 + r1 * ag1;
        const float al = pl / (rd + 1e-8f);
        sPL[p] = pl;
        bhalf8 f0;
        f0[0] = (short)f2b(x0); f0[1] = (short)f2b(x1);
        f0[2] = (short)f2b(va0); f0[3] = (short)f2b(va1);
        f0[4] = (short)f2b(al); f0[5] = (short)f2b(pl);
        f0[6] = 0; f0[7] = 0;
        bhalf8 z = {0, 0, 0, 0, 0, 0, 0, 0};
        *(bhalf8*)&sA0[p * 32 + 0] = f0;
        *(bhalf8*)&sA0[p * 32 + 8] = z;
        *(bhalf8*)&sA0[p * 32 + 16] = z;
        *(bhalf8*)&sA0[p * 32 + 24] = z;
    }
    __syncthreads();

    {
        float b0v[4];
        #pragma unroll
        for (int j = 0; j < 4; ++j) b0v[j] = ab0[j * 16 + lrow];
        bhalf8 a[4];
        #pragma unroll
        for (int mtl = 0; mtl < 4; ++mtl)
            a[mtl] = *(const bhalf8*)&sA0[(wave * 64 + mtl * 16 + lrow) * 32 + lkg * 8];
        #pragma unroll
        for (int j = 0; j < 4; ++j) {
            bhalf8 bf = *(const bhalf8*)(W0a + (j * 16 + lrow) * 32 + lkg * 8);
            #pragma unroll
            for (int mtl = 0; mtl < 4; ++mtl) {
                floatx4 c = {0.f, 0.f, 0.f, 0.f};
                c = __builtin_amdgcn_mfma_f32_16x16x32_bf16(a[mtl], bf, c, 0, 0, 0);
                #pragma unroll
                for (int q = 0; q < 4; ++q) {
                    int row = wave * 64 + mtl * 16 + lkg * 4 + q;
                    sH0[row * AH0S + j * 16 + lrow] = f2b(fast_tanh(c[q] + b0v[j]));
                }
            }
        }
    }
    __syncthreads();

    {
        float b1v[4], w2v[4];
        #pragma unroll
        for (int j = 0; j < 4; ++j) { b1v[j] = ab1[j * 16 + lrow]; w2v[j] = aw2[j * 16 + lrow]; }
        bhalf8 a0[4], a1[4];
        #pragma unroll
        for (int mtl = 0; mtl < 4; ++mtl) {
            int base = (wave * 64 + mtl * 16 + lrow) * AH0S;
            a0[mtl] = *(const bhalf8*)&sH0[base + lkg * 8];
            a1[mtl] = *(const bhalf8*)&sH0[base + 32 + lkg * 8];
        }
        float s[4][4];
        #pragma unroll
        for (int mtl = 0; mtl < 4; ++mtl)
            #pragma unroll
            for (int q = 0; q < 4; ++q) s[mtl][q] = 0.0f;
        #pragma unroll
        for (int j = 0; j < 4; ++j) {
            bhalf8 bf0 = *(const bhalf8*)(W1a + (j * 16 + lrow) * 64 + lkg * 8);
            bhalf8 bf1 = *(const bhalf8*)(W1a + (j * 16 + lrow) * 64 + 32 + lkg * 8);
            #pragma unroll
            for (int mtl = 0; mtl < 4; ++mtl) {
                floatx4 c = {0.f, 0.f, 0.f, 0.f};
                c = __builtin_amdgcn_mfma_f32_16x16x32_bf16(a0[mtl], bf0, c, 0, 0, 0);
                c = __builtin_amdgcn_mfma_f32_16x16x32_bf16(a1[mtl], bf1, c, 0, 0, 0);
                #pragma unroll
                for (int q = 0; q < 4; ++q)
                    s[mtl][q] += fast_tanh(c[q] + b1v[j]) * w2v[j];
            }
        }
        #pragma unroll
        for (int mask = 1; mask <= 8; mask <<= 1)
            #pragma unroll
            for (int mtl = 0; mtl < 4; ++mtl)
                #pragma unroll
                for (int q = 0; q < 4; ++q)
                    s[mtl][q] += __shfl_xor(s[mtl][q], mask, 64);
        if (lrow == 0) {
            #pragma unroll
            for (int mtl = 0; mtl < 4; ++mtl)
                #pragma unroll
                for (int q = 0; q < 4; ++q)
                    sLG[wave * 64 + mtl * 16 + lkg * 4 + q] = s[mtl][q];
        }
    }
    __syncthreads();

    {
        const int p = tid;
        const float ml = (sPL[p] > 0.0f) ? (sLG[p] + ab2[0]) : -1e30f;
        const int wid = wave;
        float mv = ml;
        for (int o = 32; o > 0; o >>= 1) mv = fmaxf(mv, __shfl_xor(mv, o, 64));
        if (lane == 0) s_red[wid] = mv;
        __syncthreads();
        mv = fmaxf(s_red[0], s_red[1]);

        const float ew = __expf(ml - mv);
        float sv = ew;
        for (int o = 32; o > 0; o >>= 1) sv += __shfl_xor(sv, o, 64);
        if (lane == 0) s_red[2 + wid] = sv;
        __syncthreads();
        sv = s_red[2] + s_red[3];
        const float attn = ew / sv;

        float s0 = attn * sigma[(b * PP + p) * 2 + 0];
        float s1 = attn * sigma[(b * PP + p) * 2 + 1];
        for (int o = 32; o > 0; o >>= 1) { s0 += __shfl_xor(s0, o, 64); s1 += __shfl_xor(s1, o, 64); }
        if (lane == 0) { s_red[4 + wid] = s0; s_red[6 + wid] = s1; }
        __syncthreads();

        const float cc0 = __expf(-(s_red[4] + s_red[5]));
        const float cc1 = __expf(-(s_red[6] + s_red[7]));
        const int ubase = ((b * NN + n) * KK1 + k) * 256;
        for (int cc = tid; cc < 256; cc += 128) {
            float uv = x0 * tw0[cc] + x1 * tw0[256 + cc]
                     + va0 * tw0[512 + cc] + va1 * tw0[768 + cc]
                     + cc0 * tw0[2048 + cc] + cc1 * tw0[2304 + cc];
            u_ws[ubase + cc] = f2b(uv);
        }
    }
}

// ---------------------------------------------------------------------------
// Kernel B1 (hchain): bulk GEMM, 32 rows/block over R = 139264 rows
// (row = bnm*17 + k). h0 fill K-CHUNKED (sH0 32x136); h1 full (sH1 32x264).
// LDS 25.6 KB -> 6 blocks/CU (24 waves). Occupancy is the lever: kernel is
// VALU-transcendental-bound (~59 us busy), was idling 44% at 3 blocks/CU.
// ---------------------------------------------------------------------------
__global__ __launch_bounds__(256, 6) void hchain_kernel(
    const ushort_t* __restrict__ u_ws, const ushort_t* __restrict__ w_ws,
    const ushort_t* __restrict__ W1t, const ushort_t* __restrict__ W2t,
    const float* __restrict__ tb1, const float* __restrict__ tb2,
    ushort_t* __restrict__ g_ws, ushort_t* __restrict__ gv_ws)
{
    __shared__ __align__(16) ushort_t sH0[32 * 136];   // one 128-col K-chunk
    __shared__ __align__(16) ushort_t sH1[32 * 264];   // full 256 cols

    const int tid = threadIdx.x;
    const int wave = tid >> 6;
    const int lane = tid & 63;
    const int lrow = lane & 15;
    const int lkg  = lane >> 4;
    const int R0 = blockIdx.x * 32;

    // h0-fill mapping: thread owns 1 row x 16 cols per chunk
    const int fr = tid >> 3;
    const int fcb = (tid & 7) * 16;
    const int fR = R0 + fr;
    const int fbnm = fR / 17;
    const int fk = fR - fbnm * 17;
    const int fbn = fbnm >> 6, fm = fbnm & 63;
    const ushort_t* fup = u_ws + (fbn * KK1 + fk) * 256 + fcb;
    const ushort_t* fwp = w_ws + (((fbn >> 5) << 6) + fm) * 256 + fcb;

    // ---- L1: 32 x 256, K=256 in two 128-chunks ----
    floatx4 c1[4][2];
    #pragma unroll
    for (int j = 0; j < 4; ++j)
        #pragma unroll
        for (int rt = 0; rt < 2; ++rt) c1[j][rt] = (floatx4){0.f, 0.f, 0.f, 0.f};

    for (int chunk = 0; chunk < 2; ++chunk) {
        if (chunk) __syncthreads();   // waves done reading sH0 chunk 0
        #pragma unroll
        for (int i = 0; i < 2; ++i) {
            bhalf8 uu = *(const bhalf8*)(fup + chunk * 128 + i * 8);
            bhalf8 ww = *(const bhalf8*)(fwp + chunk * 128 + i * 8);
            bhalf8 hh;
            #pragma unroll
            for (int jj = 0; jj < 8; ++jj)
                hh[jj] = (short)f2b(fast_tanh(b2f((ushort_t)uu[jj]) + b2f((ushort_t)ww[jj])));
            *(bhalf8*)&sH0[fr * 136 + fcb + i * 8] = hh;
        }
        __syncthreads();
        #pragma unroll
        for (int ksl = 0; ksl < 4; ++ksl) {
            bhalf8 a[2];
            #pragma unroll
            for (int rt = 0; rt < 2; ++rt)
                a[rt] = *(const bhalf8*)&sH0[(rt * 16 + lrow) * 136 + ksl * 32 + lkg * 8];
            #pragma unroll
            for (int j = 0; j < 4; ++j) {
                bhalf8 bf = *(const bhalf8*)(W1t + ((wave * 4 + j) * 16 + lrow) * 256
                                             + chunk * 128 + ksl * 32 + lkg * 8);
                #pragma unroll
                for (int rt = 0; rt < 2; ++rt)
                    c1[j][rt] = __builtin_amdgcn_mfma_f32_16x16x32_bf16(a[rt], bf, c1[j][rt], 0, 0, 0);
            }
        }
    }
    // L1 epilogue -> sH1
    #pragma unroll
    for (int j = 0; j < 4; ++j) {
        const int col = (wave * 4 + j) * 16 + lrow;
        const float bb = tb1[col];
        #pragma unroll
        for (int rt = 0; rt < 2; ++rt)
            #pragma unroll
            for (int q = 0; q < 4; ++q)
                sH1[(rt * 16 + lkg * 4 + q) * 264 + col] = f2b(fast_tanh(c1[j][rt][q] + bb));
    }
    __syncthreads();

    // ---- L2: 32 x 128, K=256 ----
    {
        floatx4 c2[2][2];
        #pragma unroll
        for (int j = 0; j < 2; ++j)
            #pragma unroll
            for (int rt = 0; rt < 2; ++rt) c2[j][rt] = (floatx4){0.f, 0.f, 0.f, 0.f};
        #pragma unroll
        for (int ks = 0; ks < 8; ++ks) {
            bhalf8 a[2];
            #pragma unroll
            for (int rt = 0; rt < 2; ++rt)
                a[rt] = *(const bhalf8*)&sH1[(rt * 16 + lrow) * 264 + ks * 32 + lkg * 8];
            #pragma unroll
            for (int j = 0; j < 2; ++j) {
                bhalf8 bf = *(const bhalf8*)(W2t + ((wave * 2 + j) * 16 + lrow) * 256 + ks * 32 + lkg * 8);
                #pragma unroll
                for (int rt = 0; rt < 2; ++rt)
                    c2[j][rt] = __builtin_amdgcn_mfma_f32_16x16x32_bf16(a[rt], bf, c2[j][rt], 0, 0, 0);
            }
        }
        #pragma unroll
        for (int j = 0; j < 2; ++j) {
            const int col = (wave * 2 + j) * 16 + lrow;
            const float bb = tb2[col];
            #pragma unroll
            for (int rt = 0; rt < 2; ++rt)
                #pragma unroll
                for (int q = 0; q < 4; ++q) {
                    const int R = R0 + rt * 16 + lkg * 4 + q;
                    const int bnm = R / 17;
                    const int kk = R - bnm * 17;
                    const ushort_t gq = f2b(__expf(fast_tanh(c2[j][rt][q] + bb)));
                    if (kk == 0) gv_ws[bnm * 128 + col] = gq;
                    else         g_ws[bnm * 2048 + col * 16 + (kk - 1)] = gq;
                }
        }
    }
}

// ---------------------------------------------------------------------------
// Kernel B2 (scatter): per (b,n,2m) scattering recurrence; g read from global.
// LDS ~22.6 KB; 5 barriers.
// ---------------------------------------------------------------------------
#define AS2S 136
#define V2S  40

#define U_AS   0      // 17x32 [0,544)
#define U_A2S  544    // 16x32 [544,1056)
#define U_AS2  1056   // 34x136 [1056,5680)
#define U_A3   1056   // aliases AS2 (disjoint lifetime)
#define U_V2T  5680   // 128x40 [5680,10800)
#define F_NEWV 5400   // float idx; u16 [10800,11312)
#define F_BBW  5656   // u16 [11312,11316)
#define F_RED  5658   // u16 [11316,11324)

__global__ __launch_bounds__(256, 6) void scatter_kernel(
    const float* __restrict__ boundary, const float* __restrict__ bweights,
    const float* __restrict__ vweights, const float* __restrict__ scat,
    const float* __restrict__ selfscat,
    const ushort_t* __restrict__ S0t, const ushort_t* __restrict__ S1t,
    const float* __restrict__ sb0, const float* __restrict__ sb1,
    const float* __restrict__ outw,
    const ushort_t* __restrict__ g_ws, const ushort_t* __restrict__ gv_ws,
    float* __restrict__ out)
{
    __shared__ __align__(16) ushort_t smem[11324];
    float* smf = (float*)smem;

    const int tid = threadIdx.x;
    const int wave = tid >> 6;
    const int lane = tid & 63;
    const int lrow = lane & 15;
    const int lkg  = lane >> 4;

    const int blk = blockIdx.x;
    const int b  = blk >> 10;
    const int n  = (blk >> 5) & 31;
    const int mg = blk & 31;
    const int m0 = mg * 2;
    const int bn = b * NN + n;
    const int bnm0 = bn * MM + m0;

    if (tid < 2)
        smf[F_BBW + tid] = boundary[b * MM + m0 + tid] * bweights[b * MM + m0 + tid];

    // ---- AS build (17x32: rows 0-15 rwvs, row 16 rwv; cols 16-31 zero) ----
    for (int idx = tid; idx < 17 * 32; idx += 256) {
        int i = idx >> 5, c = idx & 31;
        float val = 0.0f;
        if (c < 16) {
            float vw = vweights[b * KK + c];
            val = (i < 16) ? (1.0f - selfscat[(b * KK + i) * KK + c]) * vw
                           : (1.0f - scat[bn * KK + c]) * vw;
        }
        smem[U_AS + idx] = f2b(val);
    }
    // ---- A2S build (block-diag rwv; rest zero) ----
    for (int idx = tid; idx < 512; idx += 256) {
        int r = idx >> 5, c = idx & 31;
        float val = 0.0f;
        if ((c >> 4) == r) {
            int cc = c & 15;
            val = (1.0f - scat[bn * KK + cc]) * vweights[b * KK + cc];
        }
        smem[U_A2S + idx] = f2b(val);
    }
    __syncthreads();

    // ---- resvs: AS @ g(global, k-contig) -> AS2 ----
    {
        bhalf8 a0 = *(const bhalf8*)&smem[U_AS + lrow * 32 + lkg * 8];
        bhalf8 a1 = *(const bhalf8*)&smem[U_AS + (16 + lrow) * 32 + lkg * 8];
        #pragma unroll
        for (int m = 0; m < 2; ++m) {
            #pragma unroll
            for (int j = 0; j < 2; ++j) {
                const int col = (wave * 2 + j) * 16 + lrow;
                bhalf8 bf = *(const bhalf8*)(g_ws + (bnm0 + m) * 2048 + col * 16 + lkg * 8);
                #pragma unroll
                for (int mt = 0; mt < 2; ++mt) {
                    floatx4 c = {0.f, 0.f, 0.f, 0.f};
                    c = __builtin_amdgcn_mfma_f32_16x16x32_bf16(mt ? a1 : a0, bf, c, 0, 0, 0);
                    #pragma unroll
                    for (int q = 0; q < 4; ++q) {
                        int ic = mt * 16 + lkg * 4 + q;
                        if (ic < 17) {
                            int r2 = (ic == 16) ? m * 17 : m * 17 + 1 + ic;
                            smem[U_AS2 + r2 * AS2S + col] = f2b(c[q]);
                        }
                    }
                }
            }
        }
    }
    __syncthreads();

    // ---- sw0: tanh(AS2@S0t+sb0) -> NEWV (fp32) / V2T (vstar2 bf16) ----
    {
        floatx4 c3[2][3];
        #pragma unroll
        for (int j = 0; j < 2; ++j)
            #pragma unroll
            for (int mt = 0; mt < 3; ++mt) c3[j][mt] = (floatx4){0.f, 0.f, 0.f, 0.f};
        #pragma unroll
        for (int ks = 0; ks < 4; ++ks) {
            bhalf8 a[3];
            #pragma unroll
            for (int mt = 0; mt < 3; ++mt)
                a[mt] = *(const bhalf8*)&smem[U_AS2 + (mt * 16 + lrow) * AS2S + ks * 32 + lkg * 8];
            #pragma unroll
            for (int j = 0; j < 2; ++j) {
                bhalf8 bf = *(const bhalf8*)(S0t + ((wave * 2 + j) * 16 + lrow) * 128 + ks * 32 + lkg * 8);
                #pragma unroll
                for (int mt = 0; mt < 3; ++mt)
                    c3[j][mt] = __builtin_amdgcn_mfma_f32_16x16x32_bf16(a[mt], bf, c3[j][mt], 0, 0, 0);
            }
        }
        #pragma unroll
        for (int j = 0; j < 2; ++j) {
            const int col = (wave * 2 + j) * 16 + lrow;
            const float bb = sb0[col];
            #pragma unroll
            for (int mt = 0; mt < 3; ++mt)
                #pragma unroll
                for (int q = 0; q < 4; ++q) {
                    int r2 = mt * 16 + lkg * 4 + q;
                    if (r2 < 34) {
                        int m = (r2 >= 17);
                        int i2 = r2 - m * 17;
                        float val = fast_tanh(c3[j][mt][q] + bb);
                        if (i2 == 0) {
                            float gv = b2f(gv_ws[(bnm0 + m) * 128 + col]);
                            smf[F_NEWV + m * 128 + col] = gv + val;
                        } else {
                            int j2 = i2 - 1;
                            float gvs = b2f(g_ws[(bnm0 + m) * 2048 + col * 16 + j2]);
                            smem[U_V2T + col * V2S + m * 16 + j2] = f2b(gvs + val);
                        }
                    }
                }
        }
    }
    __syncthreads();

    // ---- resv2: A2S @ V2T -> A3 (over dead AS2) ----
    {
        bhalf8 a = *(const bhalf8*)&smem[U_A2S + lrow * 32 + lkg * 8];
        #pragma unroll
        for (int j = 0; j < 2; ++j) {
            const int col = (wave * 2 + j) * 16 + lrow;
            bhalf8 bf = *(const bhalf8*)&smem[U_V2T + col * V2S + lkg * 8];
            floatx4 c = {0.f, 0.f, 0.f, 0.f};
            c = __builtin_amdgcn_mfma_f32_16x16x32_bf16(a, bf, c, 0, 0, 0);
            #pragma unroll
            for (int q = 0; q < 4; ++q)
                smem[U_A3 + (lkg * 4 + q) * AS2S + col] = f2b(c[q]);
        }
    }
    __syncthreads();

    // ---- green + output ----
    float acc = 0.0f;
    {
        bhalf8 a[4];
        #pragma unroll
        for (int ks = 0; ks < 4; ++ks)
            a[ks] = *(const bhalf8*)&smem[U_A3 + lrow * AS2S + ks * 32 + lkg * 8];
        #pragma unroll
        for (int j = 0; j < 2; ++j) {
            const int col = (wave * 2 + j) * 16 + lrow;
            const float s1v = sb1[col];
            const float owv = outw[col];
            floatx4 c = {0.f, 0.f, 0.f, 0.f};
            #pragma unroll
            for (int ks = 0; ks < 4; ++ks) {
                bhalf8 bf = *(const bhalf8*)(S1t + col * 128 + ks * 32 + lkg * 8);
                c = __builtin_amdgcn_mfma_f32_16x16x32_bf16(a[ks], bf, c, 0, 0, 0);
            }
            #pragma unroll
            for (int q = 0; q < 4; ++q) {
                int r = lkg * 4 + q;
                if (r < 2) {
                    float green = smf[F_NEWV + r * 128 + col] + fast_tanh(c[q] + s1v);
                    acc += green * owv * smf[F_BBW + r];
                }
            }
        }
    }
    for (int o = 32; o > 0; o >>= 1) acc += __shfl_xor(acc, o, 64);
    if (lane == 0) smf[F_RED + wave] = acc;
    __syncthreads();
    if (tid == 0) {
        float tot = smf[F_RED + 0] + smf[F_RED + 1] + smf[F_RED + 2] + smf[F_RED + 3];
        atomicAdd(&out[bn], tot);
    }
}

extern "C" void kernel_launch(void* const* d_in, const int* in_sizes, int n_in,
                              void* d_out, int out_size, void* d_ws, size_t ws_size,
                              hipStream_t stream) {
    const float* phase    = (const float*)d_in[0];
    const float* bcoord   = (const float*)d_in[1];
    const float* boundary = (const float*)d_in[2];
    const float* bweights = (const float*)d_in[3];
    const float* posc     = (const float*)d_in[4];
    const float* sigma    = (const float*)d_in[5];
    const float* velc     = (const float*)d_in[6];
    const float* vweights = (const float*)d_in[7];
    const float* scat     = (const float*)d_in[8];
    const float* selfscat = (const float*)d_in[9];
    const float* aw0 = (const float*)d_in[10];
    const float* ab0 = (const float*)d_in[11];
    const float* aw1 = (const float*)d_in[12];
    const float* ab1 = (const float*)d_in[13];
    const float* aw2 = (const float*)d_in[14];
    const float* ab2 = (const float*)d_in[15];
    const float* tw0 = (const float*)d_in[16];
    const float* tb0 = (const float*)d_in[17];
    const float* tw1 = (const float*)d_in[18];
    const float* tb1 = (const float*)d_in[19];
    const float* tw2 = (const float*)d_in[20];
    const float* tb2 = (const float*)d_in[21];
    const float* sw0 = (const float*)d_in[22];
    const float* sb0 = (const float*)d_in[23];
    const float* sw1 = (const float*)d_in[24];
    const float* sb1 = (const float*)d_in[25];
    const float* outw = (const float*)d_in[26];

    float* out = (float*)d_out;
    char* ws = (char*)d_ws;
    ushort_t* W1t   = (ushort_t*)(ws + 0);          // 131072 B
    ushort_t* W2t   = (ushort_t*)(ws + 131072);     // 65536 B
    ushort_t* S0t   = (ushort_t*)(ws + 196608);     // 32768 B
    ushort_t* S1t   = (ushort_t*)(ws + 229376);     // 32768 B
    ushort_t* W0a   = (ushort_t*)(ws + 262144);     // 4096 B
    ushort_t* W1a   = (ushort_t*)(ws + 266240);     // 8192 B
    ushort_t* u_ws  = (ushort_t*)(ws + 274432);     // 1114112 B
    ushort_t* w_ws  = (ushort_t*)(ws + 1388544);    // 131072 B
    ushort_t* gv_ws = (ushort_t*)(ws + 1519616);    // 2097152 B
    ushort_t* g_ws  = (ushort_t*)(ws + 3616768);    // 33554432 B -> ~37.2 MB total

    hipMemsetAsync(d_out, 0, (size_t)out_size * sizeof(float), stream);

    prep_kernel<<<792, 256, 0, stream>>>(tw0, tw1, tw2, sw0, sw1, aw0, aw1, tb0, bcoord,
                                         W1t, W2t, S0t, S1t, W0a, W1a, w_ws);

    attn_kernel<<<BB * NN * KK1, 128, 0, stream>>>(
        phase, posc, sigma, velc, W0a, W1a, ab0, ab1, aw2, ab2, tw0, u_ws);

    hchain_kernel<<<4352, 256, 0, stream>>>(
        u_ws, w_ws, W1t, W2t, tb1, tb2, g_ws, gv_ws);

    scatter_kernel<<<BB * NN * 32, 256, 0, stream>>>(
        boundary, bweights, vweights, scat, selfscat,
        S0t, S1t, sb0, sb1, outw, g_ws, gv_ws, out);
}

// Round 10
// 285.845 us; speedup vs baseline: 1.1802x; 1.1802x over previous
//
#include <hip/hip_runtime.h>
#include <hip/hip_bf16.h>

#define BB 4
#define NN 32
#define MM 64
#define KK 16
#define KK1 17
#define PP 128
#define CC 2

typedef unsigned short ushort_t;
typedef unsigned int uint32;
typedef __attribute__((ext_vector_type(8))) short bhalf8;
typedef __attribute__((ext_vector_type(4))) float floatx4;

__device__ __forceinline__ float fast_tanh(float x) {
    float e = __expf(2.0f * x);
    return 1.0f - 2.0f / (e + 1.0f);
}
__device__ __forceinline__ ushort_t f2b(float f) {
    uint32 u = __float_as_uint(f);
    return (ushort_t)((u + 0x8000u) >> 16);
}
__device__ __forceinline__ float b2f(ushort_t h) {
    return __uint_as_float(((uint32)h) << 16);
}

// ---------------------------------------------------------------------------
// Prep: weights -> bf16 B-operand layouts + w_ws[b*64+m][256] = xp,vp part of
// L0 pre-activation with tb0 folded in (bf16).
// ---------------------------------------------------------------------------
__global__ void prep_kernel(const float* __restrict__ tw0, const float* __restrict__ tw1,
                            const float* __restrict__ tw2, const float* __restrict__ sw0,
                            const float* __restrict__ sw1, const float* __restrict__ aw0,
                            const float* __restrict__ aw1, const float* __restrict__ tb0,
                            const float* __restrict__ bcoord,
                            ushort_t* __restrict__ W1t, ushort_t* __restrict__ W2t,
                            ushort_t* __restrict__ S0t, ushort_t* __restrict__ S1t,
                            ushort_t* __restrict__ W0a, ushort_t* __restrict__ W1a,
                            ushort_t* __restrict__ w_ws) {
    int i = blockIdx.x * 256 + threadIdx.x;
    if (i < 65536) {
        int nn = i >> 8, k = i & 255;
        W1t[i] = f2b(tw1[k * 256 + nn]);
    } else if (i < 98304) {
        int j = i - 65536; int nn = j >> 8, k = j & 255;
        W2t[j] = f2b(tw2[k * 128 + nn]);
    } else if (i < 114688) {
        S0t[i - 98304] = f2b(sw0[i - 98304]);
    } else if (i < 131072) {
        S1t[i - 114688] = f2b(sw1[i - 114688]);
    } else if (i < 133120) {
        int j = i - 131072; int nn = j >> 5, k = j & 31;
        W0a[j] = (k < 6) ? f2b(aw0[k * 64 + nn]) : (ushort_t)0;
    } else if (i < 137216) {
        int j = i - 133120; int nn = j >> 6, k = j & 63;
        W1a[j] = f2b(aw1[k * 64 + nn]);
    } else if (i < 202752) {
        int j = i - 137216;
        int m = j >> 8, c = j & 255;   // m = b*64 + mm
        float v = bcoord[m * 4 + 0] * tw0[4 * 256 + c]
                + bcoord[m * 4 + 1] * tw0[5 * 256 + c]
                + bcoord[m * 4 + 2] * tw0[6 * 256 + c]
                + bcoord[m * 4 + 3] * tw0[7 * 256 + c]
                + tb0[c];
        w_ws[j] = f2b(v);
    }
}

// ---------------------------------------------------------------------------
// Kernel A (MFMA attn): block per (b,n,k); 128 thr. sH0 ALIASES sA0 (A-frags
// are register-resident before L1 MFMA; extra barrier makes sA0 dead).
// LDS 19.5 KB -> 8 blocks/CU (16 waves, 50% occ; was 28.6 KB / 5 blocks).
// Also emits u_ws[bn*17+k][256] = x,vall,coeff part of transport L0 preact.
// ---------------------------------------------------------------------------
#define AH0S 72

__global__ __launch_bounds__(128, 4) void attn_kernel(
    const float* __restrict__ phase, const float* __restrict__ posc,
    const float* __restrict__ sigma, const float* __restrict__ velc,
    const ushort_t* __restrict__ W0a, const ushort_t* __restrict__ W1a,
    const float* __restrict__ ab0, const float* __restrict__ ab1,
    const float* __restrict__ aw2, const float* __restrict__ ab2,
    const float* __restrict__ tw0, ushort_t* __restrict__ u_ws)
{
    __shared__ __align__(16) ushort_t sAH[128 * AH0S];  // sA0 (stride 32) then sH0 (stride 72)
    __shared__ float sPL[128];
    __shared__ float sLG[128];
    __shared__ float s_red[8];

    const int tid = threadIdx.x;
    const int wave = tid >> 6;
    const int lane = tid & 63;
    const int lrow = lane & 15;
    const int lkg  = lane >> 4;

    const int blk = blockIdx.x;
    const int b = blk / (NN * KK1);
    const int rem = blk % (NN * KK1);
    const int n = rem / KK1;
    const int k = rem % KK1;

    float x0, x1, va0, va1;
    {
        const int p = tid;
        x0 = phase[(b * NN + n) * 4 + 0];
        x1 = phase[(b * NN + n) * 4 + 1];
        if (k == 0) { va0 = phase[(b * NN + n) * 4 + 2]; va1 = phase[(b * NN + n) * 4 + 3]; }
        else { va0 = velc[(b * KK + (k - 1)) * 2 + 0]; va1 = velc[(b * KK + (k - 1)) * 2 + 1]; }
        const float inv = rsqrtf(va0 * va0 + va1 * va1 + 1e-16f);
        const float ag0 = va0 * inv, ag1 = va1 * inv;
        const float px = posc[(b * PP + p) * 2 + 0];
        const float py = posc[(b * PP + p) * 2 + 1];
        const float r0 = x0 - px, r1 = x1 - py;
        const float rd = sqrtf(r0 * r0 + r1 * r1 + 1e-16f);
        const float pl = r0 * ag0 + r1 * ag1;
        const float al = pl / (rd + 1e-8f);
        sPL[p] = pl;
        bhalf8 f0;
        f0[0] = (short)f2b(x0); f0[1] = (short)f2b(x1);
        f0[2] = (short)f2b(va0); f0[3] = (short)f2b(va1);
        f0[4] = (short)f2b(al); f0[5] = (short)f2b(pl);
        f0[6] = 0; f0[7] = 0;
        bhalf8 z = {0, 0, 0, 0, 0, 0, 0, 0};
        *(bhalf8*)&sAH[p * 32 + 0] = f0;
        *(bhalf8*)&sAH[p * 32 + 8] = z;   // zero pad cols (NaN-safe 0*A)
        *(bhalf8*)&sAH[p * 32 + 16] = z;
        *(bhalf8*)&sAH[p * 32 + 24] = z;
    }
    __syncthreads();

    // ---- L1: h0 = tanh(A0 @ W0a + ab0) -> sH0 (aliases sA0) ----
    {
        float b0v[4];
        #pragma unroll
        for (int j = 0; j < 4; ++j) b0v[j] = ab0[j * 16 + lrow];
        bhalf8 a[4];
        #pragma unroll
        for (int mtl = 0; mtl < 4; ++mtl)
            a[mtl] = *(const bhalf8*)&sAH[(wave * 64 + mtl * 16 + lrow) * 32 + lkg * 8];
        __syncthreads();   // all waves hold A-frags in regs; sA0 region now dead
        #pragma unroll
        for (int j = 0; j < 4; ++j) {
            bhalf8 bf = *(const bhalf8*)(W0a + (j * 16 + lrow) * 32 + lkg * 8);
            #pragma unroll
            for (int mtl = 0; mtl < 4; ++mtl) {
                floatx4 c = {0.f, 0.f, 0.f, 0.f};
                c = __builtin_amdgcn_mfma_f32_16x16x32_bf16(a[mtl], bf, c, 0, 0, 0);
                #pragma unroll
                for (int q = 0; q < 4; ++q) {
                    int row = wave * 64 + mtl * 16 + lkg * 4 + q;
                    sAH[row * AH0S + j * 16 + lrow] = f2b(fast_tanh(c[q] + b0v[j]));
                }
            }
        }
    }
    __syncthreads();

    // ---- L2 + logit ----
    {
        float b1v[4], w2v[4];
        #pragma unroll
        for (int j = 0; j < 4; ++j) { b1v[j] = ab1[j * 16 + lrow]; w2v[j] = aw2[j * 16 + lrow]; }
        bhalf8 a0[4], a1[4];
        #pragma unroll
        for (int mtl = 0; mtl < 4; ++mtl) {
            int base = (wave * 64 + mtl * 16 + lrow) * AH0S;
            a0[mtl] = *(const bhalf8*)&sAH[base + lkg * 8];
            a1[mtl] = *(const bhalf8*)&sAH[base + 32 + lkg * 8];
        }
        float s[4][4];
        #pragma unroll
        for (int mtl = 0; mtl < 4; ++mtl)
            #pragma unroll
            for (int q = 0; q < 4; ++q) s[mtl][q] = 0.0f;
        #pragma unroll
        for (int j = 0; j < 4; ++j) {
            bhalf8 bf0 = *(const bhalf8*)(W1a + (j * 16 + lrow) * 64 + lkg * 8);
            bhalf8 bf1 = *(const bhalf8*)(W1a + (j * 16 + lrow) * 64 + 32 + lkg * 8);
            #pragma unroll
            for (int mtl = 0; mtl < 4; ++mtl) {
                floatx4 c = {0.f, 0.f, 0.f, 0.f};
                c = __builtin_amdgcn_mfma_f32_16x16x32_bf16(a0[mtl], bf0, c, 0, 0, 0);
                c = __builtin_amdgcn_mfma_f32_16x16x32_bf16(a1[mtl], bf1, c, 0, 0, 0);
                #pragma unroll
                for (int q = 0; q < 4; ++q)
                    s[mtl][q] += fast_tanh(c[q] + b1v[j]) * w2v[j];
            }
        }
        #pragma unroll
        for (int mask = 1; mask <= 8; mask <<= 1)
            #pragma unroll
            for (int mtl = 0; mtl < 4; ++mtl)
                #pragma unroll
                for (int q = 0; q < 4; ++q)
                    s[mtl][q] += __shfl_xor(s[mtl][q], mask, 64);
        if (lrow == 0) {
            #pragma unroll
            for (int mtl = 0; mtl < 4; ++mtl)
                #pragma unroll
                for (int q = 0; q < 4; ++q)
                    sLG[wave * 64 + mtl * 16 + lkg * 4 + q] = s[mtl][q];
        }
    }
    __syncthreads();

    // ---- softmax + coeff -> u emit ----
    {
        const int p = tid;
        const float ml = (sPL[p] > 0.0f) ? (sLG[p] + ab2[0]) : -1e30f;
        const int wid = wave;
        float mv = ml;
        for (int o = 32; o > 0; o >>= 1) mv = fmaxf(mv, __shfl_xor(mv, o, 64));
        if (lane == 0) s_red[wid] = mv;
        __syncthreads();
        mv = fmaxf(s_red[0], s_red[1]);

        const float ew = __expf(ml - mv);
        float sv = ew;
        for (int o = 32; o > 0; o >>= 1) sv += __shfl_xor(sv, o, 64);
        if (lane == 0) s_red[2 + wid] = sv;
        __syncthreads();
        sv = s_red[2] + s_red[3];
        const float attn = ew / sv;

        float s0 = attn * sigma[(b * PP + p) * 2 + 0];
        float s1 = attn * sigma[(b * PP + p) * 2 + 1];
        for (int o = 32; o > 0; o >>= 1) { s0 += __shfl_xor(s0, o, 64); s1 += __shfl_xor(s1, o, 64); }
        if (lane == 0) { s_red[4 + wid] = s0; s_red[6 + wid] = s1; }
        __syncthreads();

        const float cc0 = __expf(-(s_red[4] + s_red[5]));
        const float cc1 = __expf(-(s_red[6] + s_red[7]));
        // u[c] = x.tw0[0:2] + vall.tw0[2:4] + coeff.tw0[8:10]
        const int ubase = ((b * NN + n) * KK1 + k) * 256;
        for (int cc = tid; cc < 256; cc += 128) {
            float uv = x0 * tw0[cc] + x1 * tw0[256 + cc]
                     + va0 * tw0[512 + cc] + va1 * tw0[768 + cc]
                     + cc0 * tw0[2048 + cc] + cc1 * tw0[2304 + cc];
            u_ws[ubase + cc] = f2b(uv);
        }
    }
}

// ---------------------------------------------------------------------------
// Kernel B: MFMA transport (R6-verified), L0 replaced by h0 = tanh(u+w) fill
// (K-chunked). LDS 40536 B -> 4 blocks/CU. 8 barriers. GTS/V2T stride 40.
// Regions (u16 idx):
//   X [0,6152):  H0A(34x136) -> GTS(128x40+8) + GV/NEWV(bf16) + A2S
//   Y [6152,15128): H1A(34x264) -> AS2(34x136) -> A3(16x136, aliases AS2)
//   Z [15128,20248): AS(17x32) -> V2T(128x40)
//   BBW/RED floats at u 20256..20268
// ---------------------------------------------------------------------------
#define H0S  136
#define H1S  264
#define GTSs 40
#define AS2S 136
#define V2S  40

#define U_H0A  0
#define U_GTS  0        // alloc 5128 (row127 tail readable)
#define U_GV   5128     // bf16 [5128,5384)
#define U_NEWV 5384     // bf16 [5384,5640)
#define U_A2S  5640     // [5640,6152)
#define U_H1A  6152
#define U_AS2  6152
#define U_A3   6152     // aliases AS2 (disjoint lifetime)
#define U_AS   15128    // [15128,15672)
#define U_V2T  15128    // [15128,20248) aliases AS (disjoint lifetime)
#define F_BBW  10128    // u 20256..20260
#define F_RED  10130    // u 20260..20268

__global__ __launch_bounds__(256, 4) void transport_kernel(
    const float* __restrict__ boundary, const float* __restrict__ bweights,
    const float* __restrict__ vweights, const float* __restrict__ scat,
    const float* __restrict__ selfscat,
    const ushort_t* __restrict__ W1t, const ushort_t* __restrict__ W2t,
    const ushort_t* __restrict__ S0t, const ushort_t* __restrict__ S1t,
    const float* __restrict__ tb1, const float* __restrict__ tb2,
    const float* __restrict__ sb0, const float* __restrict__ sb1,
    const float* __restrict__ outw,
    const ushort_t* __restrict__ u_ws, const ushort_t* __restrict__ w_ws,
    float* __restrict__ out)
{
    __shared__ __align__(16) ushort_t smem[20268];
    float* smf = (float*)smem;

    const int tid = threadIdx.x;
    const int wave = tid >> 6;
    const int lane = tid & 63;
    const int lrow = lane & 15;
    const int lkg  = lane >> 4;

    const int blk = blockIdx.x;
    const int b  = blk >> 10;
    const int n  = (blk >> 5) & 31;
    const int mg = blk & 31;
    const int m0 = mg * 2;
    const int bn = b * NN + n;

    if (tid < 2)
        smf[F_BBW + tid] = boundary[b * MM + m0 + tid] * bweights[b * MM + m0 + tid];

    // ---- AS build (Z) ----
    for (int idx = tid; idx < 17 * 32; idx += 256) {
        int i = idx >> 5, c = idx & 31;
        float val = 0.0f;
        if (c < 16) {
            float vw = vweights[b * KK + c];
            val = (i < 16) ? (1.0f - selfscat[(b * KK + i) * KK + c]) * vw
                           : (1.0f - scat[bn * KK + c]) * vw;
        }
        smem[U_AS + idx] = f2b(val);
    }

    // ---- L1 with K-chunked h0 fill (no L0 MFMA: h0 = tanh(u+w)) ----
    floatx4 c1[4][3];
    #pragma unroll
    for (int j = 0; j < 4; ++j)
        #pragma unroll
        for (int mt = 0; mt < 3; ++mt) c1[j][mt] = (floatx4){0.f, 0.f, 0.f, 0.f};

    for (int chunk = 0; chunk < 2; ++chunk) {
        if (chunk) __syncthreads();   // waves done reading H0A chunk0
        for (int idx = tid; idx < 34 * 16; idx += 256) {
            int row = idx >> 4, oct = idx & 15;
            int ml = (row >= 17);
            int k = row - ml * 17;
            bhalf8 uu = *(const bhalf8*)(u_ws + (bn * KK1 + k) * 256 + chunk * 128 + oct * 8);
            bhalf8 ww = *(const bhalf8*)(w_ws + (b * MM + m0 + ml) * 256 + chunk * 128 + oct * 8);
            bhalf8 hh;
            #pragma unroll
            for (int jj = 0; jj < 8; ++jj)
                hh[jj] = (short)f2b(fast_tanh(b2f((ushort_t)uu[jj]) + b2f((ushort_t)ww[jj])));
            *(bhalf8*)&smem[U_H0A + row * H0S + oct * 8] = hh;
        }
        __syncthreads();
        #pragma unroll
        for (int ksl = 0; ksl < 4; ++ksl) {
            bhalf8 a[3];
            #pragma unroll
            for (int mt = 0; mt < 3; ++mt)
                a[mt] = *(const bhalf8*)&smem[U_H0A + (mt * 16 + lrow) * H0S + ksl * 32 + lkg * 8];
            #pragma unroll
            for (int j = 0; j < 4; ++j) {
                bhalf8 bf = *(const bhalf8*)(W1t + ((4 * wave + j) * 16 + lrow) * 256
                                             + chunk * 128 + ksl * 32 + lkg * 8);
                #pragma unroll
                for (int mt = 0; mt < 3; ++mt)
                    c1[j][mt] = __builtin_amdgcn_mfma_f32_16x16x32_bf16(a[mt], bf, c1[j][mt], 0, 0, 0);
            }
        }
    }
    // L1 epilogue -> H1A (Y)
    {
        #pragma unroll
        for (int j = 0; j < 4; ++j) {
            float bb = tb1[(4 * wave + j) * 16 + lrow];
            #pragma unroll
            for (int mt = 0; mt < 3; ++mt)
                #pragma unroll
                for (int q = 0; q < 4; ++q) {
                    int row = mt * 16 + lkg * 4 + q;
                    if (row < 34)
                        smem[U_H1A + row * H1S + (4 * wave + j) * 16 + lrow] =
                            f2b(fast_tanh(c1[j][mt][q] + bb));
                }
        }
    }
    __syncthreads();

    // ---- L2: g = exp(tanh(h1A@W2t+tb2)) -> GTS/GV (X). Zero GTS pad cells. ----
    for (int idx = tid; idx < 1032; idx += 256) {
        int pos = (idx < 1024) ? ((idx >> 3) * GTSs + 32 + (idx & 7)) : (5120 + idx - 1024);
        smem[U_GTS + pos] = 0;
    }
    {
        floatx4 c2[2][3];
        #pragma unroll
        for (int j = 0; j < 2; ++j)
            #pragma unroll
            for (int mt = 0; mt < 3; ++mt) c2[j][mt] = (floatx4){0.f, 0.f, 0.f, 0.f};
        #pragma unroll
        for (int ks = 0; ks < 8; ++ks) {
            bhalf8 a[3];
            #pragma unroll
            for (int mt = 0; mt < 3; ++mt)
                a[mt] = *(const bhalf8*)&smem[U_H1A + (mt * 16 + lrow) * H1S + ks * 32 + lkg * 8];
            #pragma unroll
            for (int j = 0; j < 2; ++j) {
                bhalf8 bf = *(const bhalf8*)(W2t + ((2 * wave + j) * 16 + lrow) * 256 + ks * 32 + lkg * 8);
                #pragma unroll
                for (int mt = 0; mt < 3; ++mt)
                    c2[j][mt] = __builtin_amdgcn_mfma_f32_16x16x32_bf16(a[mt], bf, c2[j][mt], 0, 0, 0);
            }
        }
        #pragma unroll
        for (int j = 0; j < 2; ++j) {
            float bb = tb2[(2 * wave + j) * 16 + lrow];
            #pragma unroll
            for (int mt = 0; mt < 3; ++mt)
                #pragma unroll
                for (int q = 0; q < 4; ++q) {
                    int row = mt * 16 + lkg * 4 + q;
                    if (row < 34) {
                        int ml = (row >= 17);
                        int k = row - ml * 17;
                        int col = (2 * wave + j) * 16 + lrow;
                        float g = __expf(fast_tanh(c2[j][mt][q] + bb));
                        if (k == 0) smem[U_GV + ml * 128 + col] = f2b(g);
                        else        smem[U_GTS + col * GTSs + ml * 16 + (k - 1)] = f2b(g);
                    }
                }
        }
    }
    __syncthreads();

    // ---- resvs (AS @ GTS -> AS2) + A2S build ----
    for (int idx = tid; idx < 512; idx += 256) {
        int r = idx >> 5, c = idx & 31;
        smem[U_A2S + idx] = ((c >> 4) == r) ? smem[U_AS + 16 * 32 + (c & 15)] : (ushort_t)0;
    }
    {
        bhalf8 a0 = *(const bhalf8*)&smem[U_AS + lrow * 32 + lkg * 8];
        bhalf8 a1 = *(const bhalf8*)&smem[U_AS + (16 + lrow) * 32 + lkg * 8];
        for (int m = 0; m < 2; ++m) {
            #pragma unroll
            for (int j = 0; j < 2; ++j) {
                int nt = 2 * wave + j;
                bhalf8 bf = *(const bhalf8*)&smem[U_GTS + (nt * 16 + lrow) * GTSs + m * 16 + lkg * 8];
                #pragma unroll
                for (int mt = 0; mt < 2; ++mt) {
                    floatx4 c = {0.f, 0.f, 0.f, 0.f};
                    c = __builtin_amdgcn_mfma_f32_16x16x32_bf16(mt ? a1 : a0, bf, c, 0, 0, 0);
                    #pragma unroll
                    for (int q = 0; q < 4; ++q) {
                        int ic = mt * 16 + lkg * 4 + q;
                        if (ic < 17) {
                            int r2 = (ic == 16) ? m * 17 : m * 17 + 1 + ic;
                            smem[U_AS2 + r2 * AS2S + nt * 16 + lrow] = f2b(c[q]);
                        }
                    }
                }
            }
        }
    }
    __syncthreads();

    // ---- sw0: tanh(AS2@S0t+sb0) -> NEWV(bf16, X) / V2T(Z) ----
    {
        floatx4 c3[2][3];
        #pragma unroll
        for (int j = 0; j < 2; ++j)
            #pragma unroll
            for (int mt = 0; mt < 3; ++mt) c3[j][mt] = (floatx4){0.f, 0.f, 0.f, 0.f};
        #pragma unroll
        for (int ks = 0; ks < 4; ++ks) {
            bhalf8 a[3];
            #pragma unroll
            for (int mt = 0; mt < 3; ++mt)
                a[mt] = *(const bhalf8*)&smem[U_AS2 + (mt * 16 + lrow) * AS2S + ks * 32 + lkg * 8];
            #pragma unroll
            for (int j = 0; j < 2; ++j) {
                bhalf8 bf = *(const bhalf8*)(S0t + ((2 * wave + j) * 16 + lrow) * 128 + ks * 32 + lkg * 8);
                #pragma unroll
                for (int mt = 0; mt < 3; ++mt)
                    c3[j][mt] = __builtin_amdgcn_mfma_f32_16x16x32_bf16(a[mt], bf, c3[j][mt], 0, 0, 0);
            }
        }
        #pragma unroll
        for (int j = 0; j < 2; ++j) {
            float bb = sb0[(2 * wave + j) * 16 + lrow];
            #pragma unroll
            for (int mt = 0; mt < 3; ++mt)
                #pragma unroll
                for (int q = 0; q < 4; ++q) {
                    int r2 = mt * 16 + lkg * 4 + q;
                    if (r2 < 34) {
                        int m = (r2 >= 17);
                        int i2 = r2 - m * 17;
                        int col = (2 * wave + j) * 16 + lrow;
                        float val = fast_tanh(c3[j][mt][q] + bb);
                        if (i2 == 0) {
                            smem[U_NEWV + m * 128 + col] =
                                f2b(b2f(smem[U_GV + m * 128 + col]) + val);
                        } else {
                            int j2 = i2 - 1;
                            smem[U_V2T + col * V2S + m * 16 + j2] =
                                f2b(b2f(smem[U_GTS + col * GTSs + m * 16 + j2]) + val);
                        }
                    }
                }
        }
    }
    __syncthreads();

    // ---- resv2: A2S @ V2T -> A3 (Y, aliases dead AS2) ----
    {
        bhalf8 a = *(const bhalf8*)&smem[U_A2S + lrow * 32 + lkg * 8];
        #pragma unroll
        for (int j = 0; j < 2; ++j) {
            int nt = 2 * wave + j;
            bhalf8 bf = *(const bhalf8*)&smem[U_V2T + (nt * 16 + lrow) * V2S + lkg * 8];
            floatx4 c = {0.f, 0.f, 0.f, 0.f};
            c = __builtin_amdgcn_mfma_f32_16x16x32_bf16(a, bf, c, 0, 0, 0);
            #pragma unroll
            for (int q = 0; q < 4; ++q) {
                int r = lkg * 4 + q;
                smem[U_A3 + r * AS2S + nt * 16 + lrow] = f2b(c[q]);
            }
        }
    }
    __syncthreads();

    // ---- green + output ----
    float acc = 0.0f;
    {
        bhalf8 a[4];
        #pragma unroll
        for (int ks = 0; ks < 4; ++ks)
            a[ks] = *(const bhalf8*)&smem[U_A3 + lrow * AS2S + ks * 32 + lkg * 8];
        #pragma unroll
        for (int j = 0; j < 2; ++j) {
            int nt = 2 * wave + j;
            float s1v = sb1[nt * 16 + lrow];
            float owv = outw[nt * 16 + lrow];
            floatx4 c = {0.f, 0.f, 0.f, 0.f};
            #pragma unroll
            for (int ks = 0; ks < 4; ++ks) {
                bhalf8 bf = *(const bhalf8*)(S1t + (nt * 16 + lrow) * 128 + ks * 32 + lkg * 8);
                c = __builtin_amdgcn_mfma_f32_16x16x32_bf16(a[ks], bf, c, 0, 0, 0);
            }
            #pragma unroll
            for (int q = 0; q < 4; ++q) {
                int r = lkg * 4 + q;
                if (r < 2) {
                    int col = nt * 16 + lrow;
                    float green = b2f(smem[U_NEWV + r * 128 + col]) + fast_tanh(c[q] + s1v);
                    acc += green * owv * smf[F_BBW + r];
                }
            }
        }
    }
    for (int o = 32; o > 0; o >>= 1) acc += __shfl_xor(acc, o, 64);
    if (lane == 0) smf[F_RED + wave] = acc;
    __syncthreads();
    if (tid == 0) {
        float tot = smf[F_RED + 0] + smf[F_RED + 1] + smf[F_RED + 2] + smf[F_RED + 3];
        atomicAdd(&out[bn], tot);
    }
}

extern "C" void kernel_launch(void* const* d_in, const int* in_sizes, int n_in,
                              void* d_out, int out_size, void* d_ws, size_t ws_size,
                              hipStream_t stream) {
    const float* phase    = (const float*)d_in[0];
    const float* bcoord   = (const float*)d_in[1];
    const float* boundary = (const float*)d_in[2];
    const float* bweights = (const float*)d_in[3];
    const float* posc     = (const float*)d_in[4];
    const float* sigma    = (const float*)d_in[5];
    const float* velc     = (const float*)d_in[6];
    const float* vweights = (const float*)d_in[7];
    const float* scat     = (const float*)d_in[8];
    const float* selfscat = (const float*)d_in[9];
    const float* aw0 = (const float*)d_in[10];
    const float* ab0 = (const float*)d_in[11];
    const float* aw1 = (const float*)d_in[12];
    const float* ab1 = (const float*)d_in[13];
    const float* aw2 = (const float*)d_in[14];
    const float* ab2 = (const float*)d_in[15];
    const float* tw0 = (const float*)d_in[16];
    const float* tb0 = (const float*)d_in[17];
    const float* tw1 = (const float*)d_in[18];
    const float* tb1 = (const float*)d_in[19];
    const float* tw2 = (const float*)d_in[20];
    const float* tb2 = (const float*)d_in[21];
    const float* sw0 = (const float*)d_in[22];
    const float* sb0 = (const float*)d_in[23];
    const float* sw1 = (const float*)d_in[24];
    const float* sb1 = (const float*)d_in[25];
    const float* outw = (const float*)d_in[26];

    float* out = (float*)d_out;
    char* ws = (char*)d_ws;
    ushort_t* W1t  = (ushort_t*)(ws + 0);         // 131072 B
    ushort_t* W2t  = (ushort_t*)(ws + 131072);    // 65536 B
    ushort_t* S0t  = (ushort_t*)(ws + 196608);    // 32768 B
    ushort_t* S1t  = (ushort_t*)(ws + 229376);    // 32768 B
    ushort_t* W0a  = (ushort_t*)(ws + 262144);    // 4096 B
    ushort_t* W1a  = (ushort_t*)(ws + 266240);    // 8192 B
    ushort_t* u_ws = (ushort_t*)(ws + 274432);    // 2176*256*2 = 1114112 B
    ushort_t* w_ws = (ushort_t*)(ws + 1388544);   // 256*256*2 = 131072 B -> 1519616 total

    hipMemsetAsync(d_out, 0, (size_t)out_size * sizeof(float), stream);

    prep_kernel<<<792, 256, 0, stream>>>(tw0, tw1, tw2, sw0, sw1, aw0, aw1, tb0, bcoord,
                                         W1t, W2t, S0t, S1t, W0a, W1a, w_ws);

    attn_kernel<<<BB * NN * KK1, 128, 0, stream>>>(
        phase, posc, sigma, velc, W0a, W1a, ab0, ab1, aw2, ab2, tw0, u_ws);

    transport_kernel<<<BB * NN * 32, 256, 0, stream>>>(
        boundary, bweights, vweights, scat, selfscat,
        W1t, W2t, S0t, S1t, tb1, tb2, sb0, sb1, outw, u_ws, w_ws, out);
}